// Round 10
// baseline (158.662 us; speedup 1.0000x reference)
//
#include <hip/hip_runtime.h>

#define BATCH 8
#define S_LEN 2048
#define DDIM 512
#define UDIM 512
#define WIN_L 128
#define WIN_R 128
#define PP 296   // P LDS pitch (f16): 288 + 8 (rows shift banks by 148%32=20 -> spread)

typedef _Float16 f16;
typedef __attribute__((ext_vector_type(8))) _Float16 f16x8;
typedef __attribute__((ext_vector_type(4))) _Float16 f16x4;
typedef __attribute__((ext_vector_type(4))) float f32x4;

__device__ __forceinline__ void gload_lds16(const void* g, void* l) {
  __builtin_amdgcn_global_load_lds((const __attribute__((address_space(1))) void*)g,
                                   (__attribute__((address_space(3))) void*)l, 16, 0, 0);
}

#define BARR  __builtin_amdgcn_s_barrier()
#define SCHB  __builtin_amdgcn_sched_barrier(0)
#define WAITV4 asm volatile("s_waitcnt vmcnt(4)" ::: "memory")
#define WAITV0 asm volatile("s_waitcnt vmcnt(0)" ::: "memory")

// ---------------- prep2: W [D][U] fp32 -> WT [U][D] f16  AND  X fp32 -> X16 f16 ----------------
__global__ void prep(const float* __restrict__ Wq, const float* __restrict__ Wk,
                     const float* __restrict__ Wv, const float* __restrict__ X32,
                     f16* __restrict__ WT, f16* __restrict__ X16) {
  int id = blockIdx.x;
  if (id < 768) {
    __shared__ float t[32][33];
    int zx = id & 15, zy = (id >> 4) & 15, zz = id >> 8;
    const float* W = zz == 0 ? Wq : (zz == 1 ? Wk : Wv);
    f16* WTz = WT + (size_t)zz * DDIM * UDIM;
    int tx = threadIdx.x & 31, ty = threadIdx.x >> 5;  // 32 x 8
    int n0 = zx * 32, k0 = zy * 32;
    for (int i = 0; i < 4; i++) {
      int r = ty * 4 + i;
      t[r][tx] = W[(size_t)(k0 + r) * UDIM + n0 + tx];
    }
    __syncthreads();
    for (int i = 0; i < 4; i++) {
      int r = ty * 4 + i;
      WTz[(size_t)(n0 + r) * DDIM + k0 + tx] = (f16)t[tx][r];
    }
  } else {
    size_t i0 = ((size_t)(id - 768) * 256 + threadIdx.x) * 8;
    float4 a = *(const float4*)(X32 + i0);
    float4 b = *(const float4*)(X32 + i0 + 4);
    f16x8 o;
    o[0] = (f16)a.x; o[1] = (f16)a.y; o[2] = (f16)a.z; o[3] = (f16)a.w;
    o[4] = (f16)b.x; o[5] = (f16)b.y; o[6] = (f16)b.z; o[7] = (f16)b.w;
    *(f16x8*)(X16 + i0) = o;
  }
}

// ---------------- QKV GEMM v7 (best-total r7 version, unchanged) ----------------
__global__ __launch_bounds__(256, 3) void gemm_qkv(
    const f16* __restrict__ X16, const f16* __restrict__ WT,
    const float* __restrict__ bq, const float* __restrict__ bk, const float* __restrict__ bv,
    f16* __restrict__ QKV, f16* __restrict__ VT) {
  int g = blockIdx.x;
  int xcd = g & 7, j = g >> 3;           // j in [0,192)
  int m_blk = xcd * 16 + (j & 15);       // 0..127
  int rest = j >> 4;                     // 0..11
  int ny = rest & 3, z = rest >> 2;      // ny 0..3, z 0..2

  const f16* WTz = WT + (size_t)z * DDIM * UDIM;   // [U][D] layout
  const float* bias = z == 0 ? bq : (z == 1 ? bk : bv);
  f16* out = QKV + (size_t)z * (BATCH * S_LEN) * UDIM;

  __shared__ f16 Al[2][128 * 32];        // [chunk] 16 KB
  __shared__ f16 Bl[2][128 * 32];        // [chunk] 16 KB

  int tid = threadIdx.x, wv = tid >> 6, ln = tid & 63;
  int m0 = m_blk * 128, n0 = ny * 128;
  int wm = (wv >> 1) * 64, wn = (wv & 1) * 64;
  int lm = ln & 15, lq = ln >> 4;
  int srow = ln >> 2;
  int scol = ((ln & 3) ^ ((ln >> 3) & 3)) * 8;         // verified source swizzle
  int rsw  = (lq ^ ((lm >> 1) & 3)) * 8;               // verified read swizzle

  f32x4 acc[4][4];
#pragma unroll
  for (int mt = 0; mt < 4; mt++)
    for (int nt = 0; nt < 4; nt++)
      for (int r = 0; r < 4; r++) acc[mt][nt][r] = 0.f;

  for (int k0 = 0; k0 < DDIM; k0 += 64) {
#pragma unroll
    for (int half = 0; half < 2; half++) {
      int r0 = half * 64 + wv * 16;  // wave-uniform
#pragma unroll
      for (int cc = 0; cc < 2; cc++) {
        gload_lds16(X16 + (size_t)(m0 + r0 + srow) * DDIM + k0 + cc * 32 + scol, &Al[cc][r0 * 32]);
        gload_lds16(WTz + (size_t)(n0 + r0 + srow) * DDIM + k0 + cc * 32 + scol, &Bl[cc][r0 * 32]);
      }
    }
    __syncthreads();

#pragma unroll
    for (int cc = 0; cc < 2; cc++) {
      f16x8 af[4], bfr[4];
#pragma unroll
      for (int mt = 0; mt < 4; mt++) af[mt] = *(const f16x8*)&Al[cc][(wm + mt * 16 + lm) * 32 + rsw];
#pragma unroll
      for (int nt = 0; nt < 4; nt++) bfr[nt] = *(const f16x8*)&Bl[cc][(wn + nt * 16 + lm) * 32 + rsw];
#pragma unroll
      for (int mt = 0; mt < 4; mt++)
#pragma unroll
        for (int nt = 0; nt < 4; nt++)
          acc[mt][nt] = __builtin_amdgcn_mfma_f32_16x16x32_f16(af[mt], bfr[nt], acc[mt][nt], 0, 0, 0);
    }
    __syncthreads();
  }

  if (z == 2) {
#pragma unroll
    for (int mt = 0; mt < 4; mt++)
#pragma unroll
      for (int nt = 0; nt < 4; nt++) {
        int col = n0 + wn + nt * 16 + lm;          // u
        float bv_ = bias[col];
        int row0 = m0 + wm + mt * 16 + lq * 4;     // global s index (r=0)
        int bb = row0 >> 11, ss = row0 & 2047;
        f16x4 o;
        for (int r = 0; r < 4; r++) o[r] = (f16)(acc[mt][nt][r] + bv_);
        *(f16x4*)&VT[((size_t)bb * UDIM + col) * S_LEN + ss] = o;
      }
  } else {
#pragma unroll
    for (int mt = 0; mt < 4; mt++)
#pragma unroll
      for (int nt = 0; nt < 4; nt++) {
        int col = n0 + wn + nt * 16 + lm;
        float bv_ = bias[col];
        for (int r = 0; r < 4; r++) {
          int row = m0 + wm + mt * 16 + lq * 4 + r;
          out[(size_t)row * UDIM + col] = (f16)(acc[mt][nt][r] + bv_);
        }
      }
  }
}

// ---------------- attention v11: 256-thr / 32-q, 16 KB slabs, 67 KB LDS -> 2 blocks/CU ----------------
// r9 diagnosis: v10 was 1 block/CU (139 KB LDS) with 4x LDS-read duplication -> LDS
// reads ~52% of time, MfmaUtil 5.8%. v11: (a) 32-q blocks reuse v7b's proven
// softmax/mask/Pb/epilogue; (b) K staged as depth-split slabs [32k][256d] (16 KB,
// sacc accumulates over depth); (c) V staged as [512u][16k] slabs (16 KB) consumed
// with K=16 MFMA (v_mfma_f32_16x16x16_f16); (d) v10's ring discipline (3 slots,
// stage-ahead-2, vmcnt(4), one barrier per slab) throughout. 512 blocks all resident.
__global__ __launch_bounds__(256, 2) void attn(
    const f16* __restrict__ Q, const f16* __restrict__ K, const f16* __restrict__ VT,
    float* __restrict__ out) {
  __shared__ f16 ring[3][8192];                      // 3 x 16 KB slabs
  __shared__ f16 Pb[32 * PP];                        // 18.9 KB
  __shared__ float wmax[2][32], wsum[2][32];
  f16* R0 = ring[0];
  f16* R1 = ring[1];
  f16* R2 = ring[2];

  int tid = threadIdx.x, wv = tid >> 6, ln = tid & 63;
  int lm = ln & 15, lq = ln >> 4;
  int b = blockIdx.x, q0 = blockIdx.y * 32;
  int rh = wv >> 1, kh = wv & 1;        // q-half (16 rows), key-half (16 keys)
  const size_t base = (size_t)b * S_LEN;
  const int strip0 = q0 - WIN_L;        // keys [strip0, strip0+288): 9 x 32-key tiles

  // ---- Q fragments: rows q0+rh*16+lm, depth 512 -> 16 frags (64 VGPR), pinned ----
  f16x8 qf[16];
  {
    const f16* qrow = Q + (base + q0 + rh * 16 + lm) * (size_t)DDIM + lq * 8;
#pragma unroll
    for (int kk = 0; kk < 16; kk++) qf[kk] = *(const f16x8*)(qrow + kk * 32);
  }
  WAITV0;
  SCHB;
#pragma unroll
  for (int kk = 0; kk < 16; kk++) asm volatile("" : "+v"(qf[kk]));

  // ---- S-phase slab staging: slab (T,D) = keys [strip0+T*32,+32) x depth [D*256,+256)
  // LDS[row][c] <- G[row][c ^ ((row&7)<<2)]  (16B chunks; XOR involution, read applies same)
#define STAGE_S(T, D, DST)                                                         \
  {                                                                                \
    _Pragma("unroll") for (int i_ = 0; i_ < 4; i_++) {                             \
      int row_ = wv * 8 + i_ * 2 + (ln >> 5);                                      \
      int key_ = strip0 + (T) * 32 + row_;                                         \
      int kc_ = key_ < 0 ? 0 : (key_ > S_LEN - 1 ? S_LEN - 1 : key_);              \
      int c_ = (ln & 31) ^ ((row_ & 7) << 2);                                      \
      gload_lds16(K + (base + kc_) * (size_t)DDIM + (D) * 256 + c_ * 8,            \
                  (DST) + (wv * 8 + i_ * 2) * 256);                                \
    }                                                                              \
  }

  f32x4 sacc[9];
#pragma unroll
  for (int s = 0; s < 9; s++)
    for (int r = 0; r < 4; r++) sacc[s][r] = 0.f;

#define S_SLAB(T, D, SRC)                                                          \
  {                                                                                \
    const f16* kl_ = (SRC);                                                        \
    int rbase_ = (kh * 16 + lm) * 256;                                             \
    int sw_ = (lm & 7) << 2;                                                       \
    f32x4 s0_, s1_;                                                                \
    _Pragma("unroll") for (int r = 0; r < 4; r++) { s0_[r] = 0.f; s1_[r] = 0.f; }  \
    __builtin_amdgcn_s_setprio(1);                                                 \
    _Pragma("unroll") for (int kk = 0; kk < 8; kk += 2) {                          \
      f16x8 b0_ = *(const f16x8*)&kl_[rbase_ + (((kk) * 4 + lq) ^ sw_) * 8];       \
      f16x8 b1_ = *(const f16x8*)&kl_[rbase_ + (((kk + 1) * 4 + lq) ^ sw_) * 8];   \
      s0_ = __builtin_amdgcn_mfma_f32_16x16x32_f16(qf[(D) * 8 + kk], b0_, s0_, 0, 0, 0);     \
      s1_ = __builtin_amdgcn_mfma_f32_16x16x32_f16(qf[(D) * 8 + kk + 1], b1_, s1_, 0, 0, 0); \
    }                                                                              \
    __builtin_amdgcn_s_setprio(0);                                                 \
    _Pragma("unroll") for (int r = 0; r < 4; r++) sacc[T][r] += s0_[r] + s1_[r];   \
  }

  // ---- S pipeline: 18 slabs s=(T*2+D), slab s in R[s%3], stage s+2 into R[(s+2)%3] ----
  STAGE_S(0, 0, R0); STAGE_S(0, 1, R1);
  WAITV4; BARR; SCHB; S_SLAB(0, 0, R0); STAGE_S(1, 0, R2);
  WAITV4; BARR; SCHB; S_SLAB(0, 1, R1); STAGE_S(1, 1, R0);
  WAITV4; BARR; SCHB; S_SLAB(1, 0, R2); STAGE_S(2, 0, R1);
  WAITV4; BARR; SCHB; S_SLAB(1, 1, R0); STAGE_S(2, 1, R2);
  WAITV4; BARR; SCHB; S_SLAB(2, 0, R1); STAGE_S(3, 0, R0);
  WAITV4; BARR; SCHB; S_SLAB(2, 1, R2); STAGE_S(3, 1, R1);
  WAITV4; BARR; SCHB; S_SLAB(3, 0, R0); STAGE_S(4, 0, R2);
  WAITV4; BARR; SCHB; S_SLAB(3, 1, R1); STAGE_S(4, 1, R0);
  WAITV4; BARR; SCHB; S_SLAB(4, 0, R2); STAGE_S(5, 0, R1);
  WAITV4; BARR; SCHB; S_SLAB(4, 1, R0); STAGE_S(5, 1, R2);
  WAITV4; BARR; SCHB; S_SLAB(5, 0, R1); STAGE_S(6, 0, R0);
  WAITV4; BARR; SCHB; S_SLAB(5, 1, R2); STAGE_S(6, 1, R1);
  WAITV4; BARR; SCHB; S_SLAB(6, 0, R0); STAGE_S(7, 0, R2);
  WAITV4; BARR; SCHB; S_SLAB(6, 1, R1); STAGE_S(7, 1, R0);
  WAITV4; BARR; SCHB; S_SLAB(7, 0, R2); STAGE_S(8, 0, R1);
  WAITV4; BARR; SCHB; S_SLAB(7, 1, R0); STAGE_S(8, 1, R2);
  WAITV4; BARR; SCHB; S_SLAB(8, 0, R1);
  WAITV0; BARR; SCHB; S_SLAB(8, 1, R2);

  // ---- mask + row max (v7b verbatim) ----
  const float scale = 0.044194173824159216f;  // 1/sqrt(512)
  float mx[4] = {-1e30f, -1e30f, -1e30f, -1e30f};
#pragma unroll
  for (int s = 0; s < 9; s++) {
    int kj = strip0 + s * 32 + kh * 16 + lm;
#pragma unroll
    for (int r = 0; r < 4; r++) {
      int qi = q0 + rh * 16 + lq * 4 + r;
      float v = sacc[s][r] * scale;
      bool ok = (kj >= 0) && (kj < S_LEN) && (kj >= qi - WIN_L) && (kj <= qi + WIN_R);
      v = ok ? v : -1e30f;
      sacc[s][r] = v;
      mx[r] = fmaxf(mx[r], v);
    }
  }
#pragma unroll
  for (int r = 0; r < 4; r++) {
    mx[r] = fmaxf(mx[r], __shfl_xor(mx[r], 1));
    mx[r] = fmaxf(mx[r], __shfl_xor(mx[r], 2));
    mx[r] = fmaxf(mx[r], __shfl_xor(mx[r], 4));
    mx[r] = fmaxf(mx[r], __shfl_xor(mx[r], 8));
  }
  if (lm == 0) {
#pragma unroll
    for (int r = 0; r < 4; r++) wmax[kh][rh * 16 + lq * 4 + r] = mx[r];
  }
  __syncthreads();  // all S reads done; full drain -> ring reusable for V

  // ---- V slab staging: slab T16 = 16 keys x 512 u, layout [u][16k] ----
#define STAGE_V(T16, DST)                                                          \
  {                                                                                \
    int kc0_ = strip0 + (T16) * 16;                                                \
    kc0_ = kc0_ < 0 ? 0 : (kc0_ > S_LEN - 16 ? S_LEN - 16 : kc0_);                 \
    _Pragma("unroll") for (int i_ = 0; i_ < 4; i_++) {                             \
      int u_ = i_ * 128 + wv * 32 + (ln >> 1);                                     \
      gload_lds16(VT + ((size_t)b * UDIM + u_) * (size_t)S_LEN + kc0_ + (ln & 1) * 8, \
                  (DST) + (i_ * 128 + wv * 32) * 16);                              \
    }                                                                              \
  }

  STAGE_V(0, R0); STAGE_V(1, R1);  // drained by the next __syncthreads; hidden under exp/park

  // ---- exp + P park + row sums (v7b verbatim) ----
  float mrow[4], sum[4] = {0.f, 0.f, 0.f, 0.f};
#pragma unroll
  for (int r = 0; r < 4; r++) {
    int row = rh * 16 + lq * 4 + r;
    mrow[r] = fmaxf(wmax[0][row], wmax[1][row]);
  }
#pragma unroll
  for (int s = 0; s < 9; s++) {
#pragma unroll
    for (int r = 0; r < 4; r++) {
      float p = __expf(sacc[s][r] - mrow[r]);
      sum[r] += p;
      Pb[(rh * 16 + lq * 4 + r) * PP + s * 32 + kh * 16 + lm] = (f16)p;
    }
  }
#pragma unroll
  for (int r = 0; r < 4; r++) {
    sum[r] += __shfl_xor(sum[r], 1);
    sum[r] += __shfl_xor(sum[r], 2);
    sum[r] += __shfl_xor(sum[r], 4);
    sum[r] += __shfl_xor(sum[r], 8);
  }
  if (lm == 0) {
#pragma unroll
    for (int r = 0; r < 4; r++) wsum[kh][rh * 16 + lq * 4 + r] = sum[r];
  }
  __syncthreads();  // Pb + wsum visible; V0,V1 drained

  // ---- PV: 18 x 16-key tiles, K=16 MFMA, same ring discipline ----
  f32x4 oacc[2][8];
#pragma unroll
  for (int mt = 0; mt < 2; mt++)
    for (int nt = 0; nt < 8; nt++)
      for (int r = 0; r < 4; r++) oacc[mt][nt][r] = 0.f;

#define PV_TILE(T16, SRC)                                                          \
  {                                                                                \
    const f16* vl_ = (SRC);                                                        \
    f16x4 pf0_ = *(const f16x4*)&Pb[lm * PP + (T16) * 16 + lq * 4];                \
    f16x4 pf1_ = *(const f16x4*)&Pb[(16 + lm) * PP + (T16) * 16 + lq * 4];         \
    __builtin_amdgcn_s_setprio(1);                                                 \
    _Pragma("unroll") for (int nt = 0; nt < 8; nt++) {                             \
      f16x4 vf_ = *(const f16x4*)&vl_[(wv * 128 + nt * 16 + lm) * 16 + lq * 4];    \
      oacc[0][nt] = __builtin_amdgcn_mfma_f32_16x16x16f16(pf0_, vf_, oacc[0][nt], 0, 0, 0); \
      oacc[1][nt] = __builtin_amdgcn_mfma_f32_16x16x16f16(pf1_, vf_, oacc[1][nt], 0, 0, 0); \
    }                                                                              \
    __builtin_amdgcn_s_setprio(0);                                                 \
  }

  WAITV4; BARR; SCHB; PV_TILE(0, R0);  STAGE_V(2, R2);
  WAITV4; BARR; SCHB; PV_TILE(1, R1);  STAGE_V(3, R0);
  WAITV4; BARR; SCHB; PV_TILE(2, R2);  STAGE_V(4, R1);
  WAITV4; BARR; SCHB; PV_TILE(3, R0);  STAGE_V(5, R2);
  WAITV4; BARR; SCHB; PV_TILE(4, R1);  STAGE_V(6, R0);
  WAITV4; BARR; SCHB; PV_TILE(5, R2);  STAGE_V(7, R1);
  WAITV4; BARR; SCHB; PV_TILE(6, R0);  STAGE_V(8, R2);
  WAITV4; BARR; SCHB; PV_TILE(7, R1);  STAGE_V(9, R0);
  WAITV4; BARR; SCHB; PV_TILE(8, R2);  STAGE_V(10, R1);
  WAITV4; BARR; SCHB; PV_TILE(9, R0);  STAGE_V(11, R2);
  WAITV4; BARR; SCHB; PV_TILE(10, R1); STAGE_V(12, R0);
  WAITV4; BARR; SCHB; PV_TILE(11, R2); STAGE_V(13, R1);
  WAITV4; BARR; SCHB; PV_TILE(12, R0); STAGE_V(14, R2);
  WAITV4; BARR; SCHB; PV_TILE(13, R1); STAGE_V(15, R0);
  WAITV4; BARR; SCHB; PV_TILE(14, R2); STAGE_V(16, R1);
  WAITV4; BARR; SCHB; PV_TILE(15, R0); STAGE_V(17, R2);
  WAITV4; BARR; SCHB; PV_TILE(16, R1);
  WAITV0; BARR; SCHB; PV_TILE(17, R2);

  // ---- epilogue (v7b verbatim): O /= l, fp32 store ----
  float linv[2][4];
#pragma unroll
  for (int mt = 0; mt < 2; mt++)
    for (int r = 0; r < 4; r++) {
      int row = mt * 16 + lq * 4 + r;
      linv[mt][r] = 1.0f / (wsum[0][row] + wsum[1][row]);
    }
#pragma unroll
  for (int mt = 0; mt < 2; mt++)
    for (int nt = 0; nt < 8; nt++)
      for (int r = 0; r < 4; r++) {
        int row = q0 + mt * 16 + lq * 4 + r;
        int col = wv * 128 + nt * 16 + lm;
        out[(base + row) * (size_t)UDIM + col] = oacc[mt][nt][r] * linv[mt][r];
      }
}

extern "C" void kernel_launch(void* const* d_in, const int* in_sizes, int n_in,
                              void* d_out, int out_size, void* d_ws, size_t ws_size,
                              hipStream_t stream) {
  const float* x  = (const float*)d_in[0];
  const float* Wq = (const float*)d_in[1];
  const float* Wk = (const float*)d_in[2];
  const float* Wv = (const float*)d_in[3];
  const float* bq = (const float*)d_in[4];
  const float* bk = (const float*)d_in[5];
  const float* bv = (const float*)d_in[6];
  float* out = (float*)d_out;

  char* ws = (char*)d_ws;
  const size_t WT_BYTES  = (size_t)3 * DDIM * UDIM * 2;            // 1.5 MB
  const size_t QKV_BYTES = (size_t)3 * BATCH * S_LEN * UDIM * 2;   // 50.3 MB
  const size_t VT_BYTES  = (size_t)BATCH * S_LEN * UDIM * 2;       // 16.8 MB
  f16* WT  = (f16*)ws;
  f16* QKV = (f16*)(ws + WT_BYTES);
  f16* VT  = (f16*)(ws + WT_BYTES + QKV_BYTES);
  f16* X16 = (f16*)(ws + WT_BYTES + QKV_BYTES + VT_BYTES);

  prep<<<768 + 4096, 256, 0, stream>>>(Wq, Wk, Wv, x, WT, X16);
  gemm_qkv<<<1536, 256, 0, stream>>>(X16, WT, bq, bk, bv, QKV, VT);
  // attn: 256 thr / 32 q-rows; 512 blocks, 2/CU resident; blockIdx.x = batch -> XCD-local K/V
  attn<<<dim3(BATCH, S_LEN / 32), 256, 0, stream>>>(
      QKV, QKV + (size_t)BATCH * S_LEN * UDIM, VT, out);
}